// Round 2
// baseline (148.521 us; speedup 1.0000x reference)
//
#include <hip/hip_runtime.h>
#include <hip/hip_bf16.h>

#define B_   64
#define N_   512
#define K_   16
#define D_   128

typedef float f32x4  __attribute__((ext_vector_type(4)));
typedef short bf16x8 __attribute__((ext_vector_type(8)));

static __device__ __forceinline__ short f2bf(float x) {
    union { float f; unsigned u; } v; v.f = x;
    unsigned r = v.u + 0x7fffu + ((v.u >> 16) & 1u);  // RNE
    return (short)(r >> 16);
}
static __device__ __forceinline__ float bfbits2f(unsigned hi_bits) {
    return __uint_as_float(hi_bits);
}

// ---------------------------------------------------------------------------
// pack: B operands -> MFMA fragment order.
// Bp1: stacked [enc_w1 (K 0..127); weight (K 128..255)], K=256, 8 ks * 8 nt * 64 lanes * 8 bf16
// Bp2: enc_w2, K=128, 4 ks * 8 nt * 64 lanes * 8 bf16
// frag element j of lane l, tile nt, step ks = B[ks*32 + (l>>4)*8 + j][nt*16 + (l&15)]
// ---------------------------------------------------------------------------
__global__ __launch_bounds__(256) void pack_kernel(const float* __restrict__ enc1,
                                                   const float* __restrict__ wgt,
                                                   const float* __restrict__ enc2,
                                                   short* __restrict__ Bp1,
                                                   short* __restrict__ Bp2) {
    int tid = blockIdx.x * 256 + threadIdx.x;   // 0..6143
    short out[8];
    if (tid < 4096) {
        int l = tid & 63, nt = (tid >> 6) & 7, ks = tid >> 9;   // ks 0..7
        int k0 = ks * 32 + (l >> 4) * 8;
        int col = nt * 16 + (l & 15);
#pragma unroll
        for (int j = 0; j < 8; ++j) {
            int r = k0 + j;
            float v = (r < 128) ? enc1[r * 128 + col] : wgt[(r - 128) * 128 + col];
            out[j] = f2bf(v);
        }
        *(int4*)&Bp1[(size_t)tid * 8] = *(int4*)out;
    } else if (tid < 6144) {
        int t2 = tid - 4096;
        int l = t2 & 63, nt = (t2 >> 6) & 7, ks = t2 >> 9;      // ks 0..3
        int k0 = ks * 32 + (l >> 4) * 8;
        int col = nt * 16 + (l & 15);
#pragma unroll
        for (int j = 0; j < 8; ++j) out[j] = f2bf(enc2[(k0 + j) * 128 + col]);
        *(int4*)&Bp2[(size_t)t2 * 8] = *(int4*)out;
    }
}

// ---------------------------------------------------------------------------
// gemm1: base = [word | agg(lib,nbrL)] @ [enc1; weight]  (K=256), t1 = tanh(base)
// 512 blocks x 256 threads; block = 64 nodes; wave w -> rows 16w..16w+15
// ---------------------------------------------------------------------------
#define LDA1 264   // 256 + 8 pad -> balanced banks (stride = 33 x 16B)
__global__ __launch_bounds__(256) void gemm1(const float* __restrict__ word,
                                             const int* __restrict__ nbrL,
                                             const float* __restrict__ lib,
                                             const short* __restrict__ Bp1,
                                             float* __restrict__ base,
                                             short* __restrict__ t1) {
    __shared__ short sA[64 * LDA1];
    __shared__ int sIdx[64 * 16];
    const int tid = threadIdx.x;
    const int blk = blockIdx.x;
    const int b = blk >> 3;
    const int node0 = blk * 64;

    *(int4*)&sIdx[tid * 4] = *(const int4*)&nbrL[(size_t)node0 * 16 + tid * 4];
    __syncthreads();

    const int h = tid >> 7;        // 0..1
    const int c = tid & 127;       // column
    const float* libB = lib + (size_t)b * N_ * D_;
#pragma unroll 2
    for (int i = 0; i < 32; ++i) {
        int row = h * 32 + i;
        int gid = node0 + row;
        sA[row * LDA1 + c] = f2bf(word[(size_t)gid * D_ + c]);
        float s = 0.f;
#pragma unroll
        for (int k = 0; k < 16; ++k) {
            int idx = sIdx[row * 16 + k];
            s += libB[(size_t)idx * D_ + c];
        }
        sA[row * LDA1 + 128 + c] = f2bf(s * 0.0625f);
    }
    __syncthreads();

    const int w = tid >> 6, l = tid & 63;
    f32x4 acc[8];
#pragma unroll
    for (int nt = 0; nt < 8; ++nt) acc[nt] = (f32x4)0.f;

    const int arow = 16 * w + (l & 15);
#pragma unroll
    for (int ks = 0; ks < 8; ++ks) {
        bf16x8 a = *(const bf16x8*)&sA[arow * LDA1 + ks * 32 + (l >> 4) * 8];
        const short* bp = Bp1 + ((size_t)(ks * 8) * 64 + l) * 8;
#pragma unroll
        for (int nt = 0; nt < 8; ++nt) {
            bf16x8 bb = *(const bf16x8*)(bp + (size_t)nt * 64 * 8);
            acc[nt] = __builtin_amdgcn_mfma_f32_16x16x32_bf16(a, bb, acc[nt], 0, 0, 0);
        }
    }

    const int r0 = 16 * w + (l >> 4) * 4;
    const int cl = l & 15;
#pragma unroll
    for (int nt = 0; nt < 8; ++nt) {
        int col = nt * 16 + cl;
#pragma unroll
        for (int r = 0; r < 4; ++r) {
            size_t o = (size_t)(node0 + r0 + r) * D_ + col;
            float v = acc[nt][r];
            base[o] = v;
            t1[o] = f2bf(tanhf(v));
        }
    }
}

// ---------------------------------------------------------------------------
// gemm2: t2 = tanh(base + agg(t1,nbr) @ enc2); pooled[b] += mask .* t2 (sum over nodes)
// ---------------------------------------------------------------------------
#define LDA2 136   // 128 + 8 pad
__global__ __launch_bounds__(256) void gemm2(const short* __restrict__ t1,
                                             const int* __restrict__ nbr,
                                             const short* __restrict__ Bp2,
                                             const float* __restrict__ base,
                                             const float* __restrict__ mask,
                                             float* __restrict__ pooled) {
    __shared__ short sA[64 * LDA2];
    __shared__ int sIdx[64 * 16];
    __shared__ float pred[4][128];
    const int tid = threadIdx.x;
    const int blk = blockIdx.x;
    const int b = blk >> 3;
    const int node0 = blk * 64;

    *(int4*)&sIdx[tid * 4] = *(const int4*)&nbr[(size_t)node0 * 16 + tid * 4];
    __syncthreads();

    const int q = tid >> 6;        // 0..3
    const int cp = tid & 63;       // column pair
    const short* t1B = t1 + (size_t)b * N_ * D_;
#pragma unroll 2
    for (int i = 0; i < 16; ++i) {
        int row = q * 16 + i;
        float s0 = 0.f, s1 = 0.f;
#pragma unroll
        for (int k = 0; k < 16; ++k) {
            int idx = sIdx[row * 16 + k];
            unsigned u = *(const unsigned*)&t1B[(size_t)idx * D_ + cp * 2];
            s0 += bfbits2f(u << 16);
            s1 += bfbits2f(u & 0xffff0000u);
        }
        sA[row * LDA2 + cp * 2]     = f2bf(s0 * 0.0625f);
        sA[row * LDA2 + cp * 2 + 1] = f2bf(s1 * 0.0625f);
    }
    __syncthreads();

    const int w = tid >> 6, l = tid & 63;
    f32x4 acc[8];
#pragma unroll
    for (int nt = 0; nt < 8; ++nt) acc[nt] = (f32x4)0.f;

    const int arow = 16 * w + (l & 15);
#pragma unroll
    for (int ks = 0; ks < 4; ++ks) {
        bf16x8 a = *(const bf16x8*)&sA[arow * LDA2 + ks * 32 + (l >> 4) * 8];
        const short* bp = Bp2 + ((size_t)(ks * 8) * 64 + l) * 8;
#pragma unroll
        for (int nt = 0; nt < 8; ++nt) {
            bf16x8 bb = *(const bf16x8*)(bp + (size_t)nt * 64 * 8);
            acc[nt] = __builtin_amdgcn_mfma_f32_16x16x32_bf16(a, bb, acc[nt], 0, 0, 0);
        }
    }

    const int r0 = 16 * w + (l >> 4) * 4;
    const int cl = l & 15;
#pragma unroll
    for (int nt = 0; nt < 8; ++nt) {
        int col = nt * 16 + cl;
        float s = 0.f;
#pragma unroll
        for (int r = 0; r < 4; ++r) {
            size_t o = (size_t)(node0 + r0 + r) * D_ + col;
            float v = tanhf(base[o] + acc[nt][r]);
            s += v * mask[node0 + r0 + r];
        }
        s += __shfl_xor(s, 16);
        s += __shfl_xor(s, 32);
        if (l < 16) pred[w][col] = s;
    }
    __syncthreads();
    if (tid < 128) {
        float tot = pred[0][tid] + pred[1][tid] + pred[2][tid] + pred[3][tid];
        atomicAdd(&pooled[b * 128 + tid], tot);
    }
}

// ---------------------------------------------------------------------------
// kC: out = pooled @ weight2   (64 x 128 @ 128 x 128), fp32 vector
// ---------------------------------------------------------------------------
__global__ __launch_bounds__(128) void kC(const float* __restrict__ pooled,
                                          const float* __restrict__ w2,
                                          float* __restrict__ out) {
    const int b = blockIdx.x;
    const int t = threadIdx.x;
    __shared__ float p[D_];
    p[t] = pooled[b * D_ + t];
    __syncthreads();
    float acc = 0.f;
#pragma unroll 4
    for (int f = 0; f < D_; ++f) acc += p[f] * w2[f * D_ + t];
    out[b * D_ + t] = acc;
}

extern "C" void kernel_launch(void* const* d_in, const int* in_sizes, int n_in,
                              void* d_out, int out_size, void* d_ws, size_t ws_size,
                              hipStream_t stream) {
    const float* word_embs   = (const float*)d_in[0];
    const int*   neibors     = (const int*)d_in[1];
    const float* lib_embs    = (const float*)d_in[2];
    const int*   neibors_lib = (const int*)d_in[3];
    const float* mask        = (const float*)d_in[4];
    const float* weight      = (const float*)d_in[5];
    const float* weight2     = (const float*)d_in[6];
    const float* enc_w1      = (const float*)d_in[7];
    const float* enc_w2      = (const float*)d_in[8];
    float* out = (float*)d_out;

    char* ws = (char*)d_ws;
    float* base   = (float*)(ws);                              // 16 MB
    short* t1     = (short*)(ws + (1u << 24));                 // 8 MB bf16
    short* Bp1    = (short*)(ws + (1u << 24) + (1u << 23));    // 64 KB
    short* Bp2    = (short*)(ws + (1u << 24) + (1u << 23) + 65536);        // 32 KB
    float* pooled = (float*)(ws + (1u << 24) + (1u << 23) + 65536 + 32768); // 32 KB

    hipMemsetAsync(pooled, 0, B_ * D_ * sizeof(float), stream);
    pack_kernel<<<24, 256, 0, stream>>>(enc_w1, weight, enc_w2, Bp1, Bp2);

    const int nblk = (B_ * N_) / 64;   // 512
    gemm1<<<nblk, 256, 0, stream>>>(word_embs, neibors_lib, lib_embs, Bp1, base, t1);
    gemm2<<<nblk, 256, 0, stream>>>(t1, neibors, Bp2, base, mask, pooled);
    kC<<<B_, 128, 0, stream>>>(pooled, weight2, out);
}

// Round 3
// 99.462 us; speedup vs baseline: 1.4932x; 1.4932x over previous
//
#include <hip/hip_runtime.h>
#include <hip/hip_bf16.h>

#define B_   64
#define N_   512
#define K_   16
#define D_   128

typedef float f32x4  __attribute__((ext_vector_type(4)));
typedef short bf16x8 __attribute__((ext_vector_type(8)));

static __device__ __forceinline__ short f2bf(float x) {
    union { float f; unsigned u; } v; v.f = x;
    unsigned r = v.u + 0x7fffu + ((v.u >> 16) & 1u);  // RNE
    return (short)(r >> 16);
}
static __device__ __forceinline__ float bfbits2f(unsigned hi_bits) {
    return __uint_as_float(hi_bits);
}

// ---------------------------------------------------------------------------
// pack: B operands -> MFMA fragment order.
// Bp1: stacked [enc_w1 (K 0..127); weight (K 128..255)], K=256
// Bp2: enc_w2, K=128
// frag elem j of lane l, tile nt, step ks = B[ks*32 + (l>>4)*8 + j][nt*16 + (l&15)]
// ---------------------------------------------------------------------------
__global__ __launch_bounds__(256) void pack_kernel(const float* __restrict__ enc1,
                                                   const float* __restrict__ wgt,
                                                   const float* __restrict__ enc2,
                                                   short* __restrict__ Bp1,
                                                   short* __restrict__ Bp2) {
    int tid = blockIdx.x * 256 + threadIdx.x;   // 0..6143
    short out[8];
    if (tid < 4096) {
        int l = tid & 63, nt = (tid >> 6) & 7, ks = tid >> 9;   // ks 0..7
        int k0 = ks * 32 + (l >> 4) * 8;
        int col = nt * 16 + (l & 15);
#pragma unroll
        for (int j = 0; j < 8; ++j) {
            int r = k0 + j;
            float v = (r < 128) ? enc1[r * 128 + col] : wgt[(r - 128) * 128 + col];
            out[j] = f2bf(v);
        }
        *(int4*)&Bp1[(size_t)tid * 8] = *(int4*)out;
    } else if (tid < 6144) {
        int t2 = tid - 4096;
        int l = t2 & 63, nt = (t2 >> 6) & 7, ks = t2 >> 9;      // ks 0..3
        int k0 = ks * 32 + (l >> 4) * 8;
        int col = nt * 16 + (l & 15);
#pragma unroll
        for (int j = 0; j < 8; ++j) out[j] = f2bf(enc2[(k0 + j) * 128 + col]);
        *(int4*)&Bp2[(size_t)t2 * 8] = *(int4*)out;
    }
}

// XCD-aware swizzle: 512 blocks, 8 blocks per batch. hw%8 selects the XCD
// (round-robin dispatch), so map XCD k -> logical blocks [64k, 64k+64)
// = batches [8k, 8k+8). Per-XCD L2 working set drops to ~2-3 MB (fits 4 MiB).
static __device__ __forceinline__ int swz_blk() {
    const int hw = blockIdx.x;
    return ((hw & 7) << 6) + (hw >> 3);
}

// ---------------------------------------------------------------------------
// gemm1: base = [word | agg(lib,nbrL)] @ [enc1; weight]  (K=256), t1 = tanh(base)
// 512 blocks x 256 threads; block = 64 nodes.
// ---------------------------------------------------------------------------
#define LDA1 264   // 256 + 8 pad
__global__ __launch_bounds__(256) void gemm1(const float* __restrict__ word,
                                             const int* __restrict__ nbrL,
                                             const float* __restrict__ lib,
                                             const short* __restrict__ Bp1,
                                             float* __restrict__ base,
                                             short* __restrict__ t1) {
    __shared__ short sA[64 * LDA1];
    __shared__ int sIdx[64 * 16];
    const int tid = threadIdx.x;
    const int blk = swz_blk();
    const int b = blk >> 3;
    const int node0 = blk * 64;

    *(int4*)&sIdx[tid * 4] = *(const int4*)&nbrL[(size_t)node0 * 16 + tid * 4];
    __syncthreads();

    const int q = tid >> 6;        // 0..3 -> rows 16q..16q+15
    const int l = tid & 63;
    const float* libB = lib + (size_t)b * N_ * D_;
#pragma unroll 2
    for (int i = 0; i < 16; ++i) {
        int row = q * 16 + i;
        int gid = node0 + row;
        float2 wv = *(const float2*)&word[(size_t)gid * D_ + l * 2];
        sA[row * LDA1 + l * 2]     = f2bf(wv.x);
        sA[row * LDA1 + l * 2 + 1] = f2bf(wv.y);
        float s0 = 0.f, s1 = 0.f;
#pragma unroll
        for (int k = 0; k < 16; ++k) {
            int idx = sIdx[row * 16 + k];
            float2 lv = *(const float2*)&libB[(size_t)idx * D_ + l * 2];
            s0 += lv.x; s1 += lv.y;
        }
        sA[row * LDA1 + 128 + l * 2]     = f2bf(s0 * 0.0625f);
        sA[row * LDA1 + 128 + l * 2 + 1] = f2bf(s1 * 0.0625f);
    }
    __syncthreads();

    const int w = tid >> 6;
    f32x4 acc[8];
#pragma unroll
    for (int nt = 0; nt < 8; ++nt) acc[nt] = (f32x4)0.f;

    const int arow = 16 * w + (l & 15);
#pragma unroll
    for (int ks = 0; ks < 8; ++ks) {
        bf16x8 a = *(const bf16x8*)&sA[arow * LDA1 + ks * 32 + (l >> 4) * 8];
        const short* bp = Bp1 + ((size_t)(ks * 8) * 64 + l) * 8;
#pragma unroll
        for (int nt = 0; nt < 8; ++nt) {
            bf16x8 bb = *(const bf16x8*)(bp + (size_t)nt * 64 * 8);
            acc[nt] = __builtin_amdgcn_mfma_f32_16x16x32_bf16(a, bb, acc[nt], 0, 0, 0);
        }
    }

    const int r0 = 16 * w + (l >> 4) * 4;
    const int cl = l & 15;
#pragma unroll
    for (int nt = 0; nt < 8; ++nt) {
        int col = nt * 16 + cl;
#pragma unroll
        for (int r = 0; r < 4; ++r) {
            size_t o = (size_t)(node0 + r0 + r) * D_ + col;
            float v = acc[nt][r];
            base[o] = v;
            t1[o] = f2bf(tanhf(v));
        }
    }
}

// ---------------------------------------------------------------------------
// gemm2: t2 = tanh(base + agg(t1,nbr) @ enc2); pooled[b] += mask .* t2
// ---------------------------------------------------------------------------
#define LDA2 136   // 128 + 8 pad
__global__ __launch_bounds__(256) void gemm2(const short* __restrict__ t1,
                                             const int* __restrict__ nbr,
                                             const short* __restrict__ Bp2,
                                             const float* __restrict__ base,
                                             const float* __restrict__ mask,
                                             float* __restrict__ pooled) {
    __shared__ short sA[64 * LDA2];
    __shared__ int sIdx[64 * 16];
    __shared__ float pred[4][128];
    const int tid = threadIdx.x;
    const int blk = swz_blk();
    const int b = blk >> 3;
    const int node0 = blk * 64;

    *(int4*)&sIdx[tid * 4] = *(const int4*)&nbr[(size_t)node0 * 16 + tid * 4];
    __syncthreads();

    const int q = tid >> 6;        // 0..3
    const int cp = tid & 63;       // column pair
    const short* t1B = t1 + (size_t)b * N_ * D_;
#pragma unroll 2
    for (int i = 0; i < 16; ++i) {
        int row = q * 16 + i;
        float s0 = 0.f, s1 = 0.f;
#pragma unroll
        for (int k = 0; k < 16; ++k) {
            int idx = sIdx[row * 16 + k];
            unsigned u = *(const unsigned*)&t1B[(size_t)idx * D_ + cp * 2];
            s0 += bfbits2f(u << 16);
            s1 += bfbits2f(u & 0xffff0000u);
        }
        sA[row * LDA2 + cp * 2]     = f2bf(s0 * 0.0625f);
        sA[row * LDA2 + cp * 2 + 1] = f2bf(s1 * 0.0625f);
    }
    __syncthreads();

    const int w = tid >> 6, l = tid & 63;
    f32x4 acc[8];
#pragma unroll
    for (int nt = 0; nt < 8; ++nt) acc[nt] = (f32x4)0.f;

    const int arow = 16 * w + (l & 15);
#pragma unroll
    for (int ks = 0; ks < 4; ++ks) {
        bf16x8 a = *(const bf16x8*)&sA[arow * LDA2 + ks * 32 + (l >> 4) * 8];
        const short* bp = Bp2 + ((size_t)(ks * 8) * 64 + l) * 8;
#pragma unroll
        for (int nt = 0; nt < 8; ++nt) {
            bf16x8 bb = *(const bf16x8*)(bp + (size_t)nt * 64 * 8);
            acc[nt] = __builtin_amdgcn_mfma_f32_16x16x32_bf16(a, bb, acc[nt], 0, 0, 0);
        }
    }

    const int r0 = 16 * w + (l >> 4) * 4;
    const int cl = l & 15;
#pragma unroll
    for (int nt = 0; nt < 8; ++nt) {
        int col = nt * 16 + cl;
        float s = 0.f;
#pragma unroll
        for (int r = 0; r < 4; ++r) {
            size_t o = (size_t)(node0 + r0 + r) * D_ + col;
            float v = tanhf(base[o] + acc[nt][r]);
            s += v * mask[node0 + r0 + r];
        }
        s += __shfl_xor(s, 16);
        s += __shfl_xor(s, 32);
        if (l < 16) pred[w][col] = s;
    }
    __syncthreads();
    if (tid < 128) {
        float tot = pred[0][tid] + pred[1][tid] + pred[2][tid] + pred[3][tid];
        atomicAdd(&pooled[b * 128 + tid], tot);
    }
}

// ---------------------------------------------------------------------------
// kC: out = pooled @ weight2   (64 x 128 @ 128 x 128)
// ---------------------------------------------------------------------------
__global__ __launch_bounds__(128) void kC(const float* __restrict__ pooled,
                                          const float* __restrict__ w2,
                                          float* __restrict__ out) {
    const int b = blockIdx.x;
    const int t = threadIdx.x;
    __shared__ float p[D_];
    p[t] = pooled[b * D_ + t];
    __syncthreads();
    float acc = 0.f;
#pragma unroll 4
    for (int f = 0; f < D_; ++f) acc += p[f] * w2[f * D_ + t];
    out[b * D_ + t] = acc;
}

extern "C" void kernel_launch(void* const* d_in, const int* in_sizes, int n_in,
                              void* d_out, int out_size, void* d_ws, size_t ws_size,
                              hipStream_t stream) {
    const float* word_embs   = (const float*)d_in[0];
    const int*   neibors     = (const int*)d_in[1];
    const float* lib_embs    = (const float*)d_in[2];
    const int*   neibors_lib = (const int*)d_in[3];
    const float* mask        = (const float*)d_in[4];
    const float* weight2     = (const float*)d_in[6];
    const float* weight      = (const float*)d_in[5];
    const float* enc_w1      = (const float*)d_in[7];
    const float* enc_w2      = (const float*)d_in[8];
    float* out = (float*)d_out;

    char* ws = (char*)d_ws;
    float* base   = (float*)(ws);                              // 16 MB
    short* t1     = (short*)(ws + (1u << 24));                 // 8 MB bf16
    short* Bp1    = (short*)(ws + (1u << 24) + (1u << 23));    // 64 KB
    short* Bp2    = (short*)(ws + (1u << 24) + (1u << 23) + 65536);        // 32 KB
    float* pooled = (float*)(ws + (1u << 24) + (1u << 23) + 65536 + 32768); // 32 KB

    hipMemsetAsync(pooled, 0, B_ * D_ * sizeof(float), stream);
    pack_kernel<<<24, 256, 0, stream>>>(enc_w1, weight, enc_w2, Bp1, Bp2);

    const int nblk = (B_ * N_) / 64;   // 512
    gemm1<<<nblk, 256, 0, stream>>>(word_embs, neibors_lib, lib_embs, Bp1, base, t1);
    gemm2<<<nblk, 256, 0, stream>>>(t1, neibors, Bp2, base, mask, pooled);
    kC<<<B_, 128, 0, stream>>>(pooled, weight2, out);
}

// Round 4
// 51.976 us; speedup vs baseline: 2.8575x; 1.9136x over previous
//
#include <hip/hip_runtime.h>
#include <hip/hip_bf16.h>

#define B_   64
#define N_   512
#define K_   16
#define D_   128
#define NPB  32                 // nodes per block
#define G1   ((B_*N_)/NPB)      // 1024 blocks

typedef float f32x4  __attribute__((ext_vector_type(4)));
typedef short bf16x8 __attribute__((ext_vector_type(8)));

static __device__ __forceinline__ short f2bf(float x) {
    union { float f; unsigned u; } v; v.f = x;
    unsigned r = v.u + 0x7fffu + ((v.u >> 16) & 1u);  // RNE
    return (short)(r >> 16);
}
static __device__ __forceinline__ float bfbits2f(unsigned hi_bits) {
    return __uint_as_float(hi_bits);
}
// tanh(x) = 1 - 2/(e^{2x}+1); exact at +/-inf, ~1e-7 rel error
static __device__ __forceinline__ float fast_tanh(float x) {
    float e = __expf(2.f * x);
    return 1.f - 2.f * __builtin_amdgcn_rcpf(e + 1.f);
}

// ---------------------------------------------------------------------------
// pack: B operands -> MFMA fragment order.
// frag elem j of lane l, tile nt, step ks = B[ks*32 + (l>>4)*8 + j][nt*16 + (l&15)]
// ---------------------------------------------------------------------------
__global__ __launch_bounds__(256) void pack_kernel(const float* __restrict__ enc1,
                                                   const float* __restrict__ wgt,
                                                   const float* __restrict__ enc2,
                                                   short* __restrict__ Bp1,
                                                   short* __restrict__ Bp2) {
    int tid = blockIdx.x * 256 + threadIdx.x;   // 0..6143
    short out[8];
    if (tid < 4096) {
        int l = tid & 63, nt = (tid >> 6) & 7, ks = tid >> 9;   // ks 0..7
        int k0 = ks * 32 + (l >> 4) * 8;
        int col = nt * 16 + (l & 15);
#pragma unroll
        for (int j = 0; j < 8; ++j) {
            int r = k0 + j;
            float v = (r < 128) ? enc1[r * 128 + col] : wgt[(r - 128) * 128 + col];
            out[j] = f2bf(v);
        }
        *(int4*)&Bp1[(size_t)tid * 8] = *(int4*)out;
    } else if (tid < 6144) {
        int t2 = tid - 4096;
        int l = t2 & 63, nt = (t2 >> 6) & 7, ks = t2 >> 9;      // ks 0..3
        int k0 = ks * 32 + (l >> 4) * 8;
        int col = nt * 16 + (l & 15);
#pragma unroll
        for (int j = 0; j < 8; ++j) out[j] = f2bf(enc2[(k0 + j) * 128 + col]);
        *(int4*)&Bp2[(size_t)t2 * 8] = *(int4*)out;
    }
}

// XCD-aware swizzle: 1024 blocks, 16 per batch. XCD k (hw%8==k) gets logical
// blocks [128k,128k+128) = batches [8k,8k+8) -> per-XCD L2 working set ~3 MB.
static __device__ __forceinline__ int swz_blk() {
    const int hw = blockIdx.x;
    return ((hw & 7) << 7) + (hw >> 3);
}

// ---------------------------------------------------------------------------
// gemm1: base = [word | agg(lib,nbrL)] @ [enc1; weight] (K=256), t1 = tanh(base)
// 1024 blocks x 256 threads; block = 32 nodes; wave w stages rows 8w..8w+7,
// computes row-tile (w&1), col-tiles 4*(w>>1)..+3.
// ---------------------------------------------------------------------------
#define LDA1 264   // 256 + 8 pad shorts
__global__ __launch_bounds__(256) void gemm1(const float* __restrict__ word,
                                             const int* __restrict__ nbrL,
                                             const float* __restrict__ lib,
                                             const short* __restrict__ Bp1,
                                             float* __restrict__ base,
                                             short* __restrict__ t1) {
    __shared__ short sA[NPB * LDA1];
    __shared__ int sIdx[NPB * 16];
    const int tid = threadIdx.x;
    const int blk = swz_blk();
    const int b = blk >> 4;
    const int node0 = blk * NPB;

    if (tid < 128) *(int4*)&sIdx[tid * 4] = *(const int4*)&nbrL[(size_t)node0 * 16 + tid * 4];
    __syncthreads();

    const int w = tid >> 6, l = tid & 63;
    const int rh = l >> 5, c4 = l & 31;         // row-half, 4-col group
    const float* libB = lib + (size_t)b * N_ * D_;

#pragma unroll 2
    for (int p = 0; p < 4; ++p) {
        const int row = 8 * w + 2 * p + rh;
        const int gid = node0 + row;
        float4 wv = *(const float4*)&word[(size_t)gid * D_ + c4 * 4];
        short4 ws; ws.x = f2bf(wv.x); ws.y = f2bf(wv.y); ws.z = f2bf(wv.z); ws.w = f2bf(wv.w);
        *(short4*)&sA[row * LDA1 + c4 * 4] = ws;
        int idxr[16];
#pragma unroll
        for (int k = 0; k < 16; ++k) idxr[k] = sIdx[row * 16 + k];
        float4 s = {0.f, 0.f, 0.f, 0.f};
#pragma unroll
        for (int k = 0; k < 16; ++k) {
            float4 lv = *(const float4*)&libB[(size_t)idxr[k] * D_ + c4 * 4];
            s.x += lv.x; s.y += lv.y; s.z += lv.z; s.w += lv.w;
        }
        short4 as; as.x = f2bf(s.x * 0.0625f); as.y = f2bf(s.y * 0.0625f);
        as.z = f2bf(s.z * 0.0625f); as.w = f2bf(s.w * 0.0625f);
        *(short4*)&sA[row * LDA1 + 128 + c4 * 4] = as;
    }
    __syncthreads();

    const int rt = w & 1, nh = w >> 1;
    f32x4 acc[4];
#pragma unroll
    for (int j = 0; j < 4; ++j) acc[j] = (f32x4)0.f;

    const int arow = rt * 16 + (l & 15);
#pragma unroll
    for (int ks = 0; ks < 8; ++ks) {
        bf16x8 a = *(const bf16x8*)&sA[arow * LDA1 + ks * 32 + (l >> 4) * 8];
#pragma unroll
        for (int j = 0; j < 4; ++j) {
            const int nt = nh * 4 + j;
            bf16x8 bb = *(const bf16x8*)&Bp1[((size_t)(ks * 8 + nt) * 64 + l) * 8];
            acc[j] = __builtin_amdgcn_mfma_f32_16x16x32_bf16(a, bb, acc[j], 0, 0, 0);
        }
    }

    const int r0 = rt * 16 + (l >> 4) * 4;
    const int cl = l & 15;
#pragma unroll
    for (int j = 0; j < 4; ++j) {
        const int col = (nh * 4 + j) * 16 + cl;
#pragma unroll
        for (int r = 0; r < 4; ++r) {
            size_t o = (size_t)(node0 + r0 + r) * D_ + col;
            float v = acc[j][r];
            base[o] = v;
            t1[o] = f2bf(fast_tanh(v));
        }
    }
}

// ---------------------------------------------------------------------------
// gemm2: t2 = tanh(base + agg(t1,nbr) @ enc2);
//        out[b] += (sum_n mask*t2) @ weight2   (kC fused, atomic into d_out)
// ---------------------------------------------------------------------------
#define LDA2 136   // 128 + 8 pad shorts
__global__ __launch_bounds__(256) void gemm2(const short* __restrict__ t1,
                                             const int* __restrict__ nbr,
                                             const short* __restrict__ Bp2,
                                             const float* __restrict__ base,
                                             const float* __restrict__ mask,
                                             const float* __restrict__ w2,
                                             float* __restrict__ out) {
    __shared__ short sA[NPB * LDA2];
    __shared__ int sIdx[NPB * 16];
    __shared__ float pred[2][128];
    __shared__ float tot[128];
    const int tid = threadIdx.x;
    const int blk = swz_blk();
    const int b = blk >> 4;
    const int node0 = blk * NPB;

    if (tid < 128) *(int4*)&sIdx[tid * 4] = *(const int4*)&nbr[(size_t)node0 * 16 + tid * 4];
    __syncthreads();

    const int w = tid >> 6, l = tid & 63;
    const int rh = l >> 5, c4 = l & 31;
    const short* t1B = t1 + (size_t)b * N_ * D_;

#pragma unroll 2
    for (int p = 0; p < 4; ++p) {
        const int row = 8 * w + 2 * p + rh;
        int idxr[16];
#pragma unroll
        for (int k = 0; k < 16; ++k) idxr[k] = sIdx[row * 16 + k];
        float s0 = 0.f, s1 = 0.f, s2 = 0.f, s3 = 0.f;
#pragma unroll
        for (int k = 0; k < 16; ++k) {
            uint2 u = *(const uint2*)&t1B[(size_t)idxr[k] * D_ + c4 * 4];
            s0 += bfbits2f(u.x << 16); s1 += bfbits2f(u.x & 0xffff0000u);
            s2 += bfbits2f(u.y << 16); s3 += bfbits2f(u.y & 0xffff0000u);
        }
        short4 as; as.x = f2bf(s0 * 0.0625f); as.y = f2bf(s1 * 0.0625f);
        as.z = f2bf(s2 * 0.0625f); as.w = f2bf(s3 * 0.0625f);
        *(short4*)&sA[row * LDA2 + c4 * 4] = as;
    }
    __syncthreads();

    const int rt = w & 1, nh = w >> 1;
    f32x4 acc[4];
#pragma unroll
    for (int j = 0; j < 4; ++j) acc[j] = (f32x4)0.f;

    const int arow = rt * 16 + (l & 15);
#pragma unroll
    for (int ks = 0; ks < 4; ++ks) {
        bf16x8 a = *(const bf16x8*)&sA[arow * LDA2 + ks * 32 + (l >> 4) * 8];
#pragma unroll
        for (int j = 0; j < 4; ++j) {
            const int nt = nh * 4 + j;
            bf16x8 bb = *(const bf16x8*)&Bp2[((size_t)(ks * 8 + nt) * 64 + l) * 8];
            acc[j] = __builtin_amdgcn_mfma_f32_16x16x32_bf16(a, bb, acc[j], 0, 0, 0);
        }
    }

    const int r0 = rt * 16 + (l >> 4) * 4;
    const int cl = l & 15;
#pragma unroll
    for (int j = 0; j < 4; ++j) {
        const int col = (nh * 4 + j) * 16 + cl;
        float s = 0.f;
#pragma unroll
        for (int r = 0; r < 4; ++r) {
            size_t o = (size_t)(node0 + r0 + r) * D_ + col;
            float v = fast_tanh(base[o] + acc[j][r]);
            s += v * mask[node0 + r0 + r];
        }
        s += __shfl_xor(s, 16);
        s += __shfl_xor(s, 32);
        if (l < 16) pred[rt][col] = s;
    }
    __syncthreads();
    if (tid < 128) tot[tid] = pred[0][tid] + pred[1][tid];
    __syncthreads();
    if (tid < 128) {
        float a2 = 0.f;
#pragma unroll 4
        for (int f = 0; f < 128; ++f) a2 += tot[f] * w2[f * 128 + tid];
        atomicAdd(&out[b * 128 + tid], a2);
    }
}

extern "C" void kernel_launch(void* const* d_in, const int* in_sizes, int n_in,
                              void* d_out, int out_size, void* d_ws, size_t ws_size,
                              hipStream_t stream) {
    const float* word_embs   = (const float*)d_in[0];
    const int*   neibors     = (const int*)d_in[1];
    const float* lib_embs    = (const float*)d_in[2];
    const int*   neibors_lib = (const int*)d_in[3];
    const float* mask        = (const float*)d_in[4];
    const float* weight      = (const float*)d_in[5];
    const float* weight2     = (const float*)d_in[6];
    const float* enc_w1      = (const float*)d_in[7];
    const float* enc_w2      = (const float*)d_in[8];
    float* out = (float*)d_out;

    char* ws = (char*)d_ws;
    float* base = (float*)(ws);                              // 16 MB
    short* t1   = (short*)(ws + (1u << 24));                 // 8 MB bf16
    short* Bp1  = (short*)(ws + (1u << 24) + (1u << 23));    // 64 KB
    short* Bp2  = (short*)(ws + (1u << 24) + (1u << 23) + 65536);  // 32 KB

    hipMemsetAsync(out, 0, B_ * D_ * sizeof(float), stream);
    pack_kernel<<<24, 256, 0, stream>>>(enc_w1, weight, enc_w2, Bp1, Bp2);

    gemm1<<<G1, 256, 0, stream>>>(word_embs, neibors_lib, lib_embs, Bp1, base, t1);
    gemm2<<<G1, 256, 0, stream>>>(t1, neibors, Bp2, base, mask, weight2, out);
}

// Round 5
// 51.284 us; speedup vs baseline: 2.8961x; 1.0135x over previous
//
#include <hip/hip_runtime.h>
#include <hip/hip_bf16.h>

#define B_   64
#define N_   512
#define K_   16
#define D_   128
#define NPB  16                 // nodes per block
#define G1   ((B_*N_)/NPB)      // 2048 blocks

typedef float f32x4  __attribute__((ext_vector_type(4)));
typedef short bf16x8 __attribute__((ext_vector_type(8)));

static __device__ __forceinline__ short f2bf(float x) {
    union { float f; unsigned u; } v; v.f = x;
    unsigned r = v.u + 0x7fffu + ((v.u >> 16) & 1u);  // RNE
    return (short)(r >> 16);
}
static __device__ __forceinline__ float bfbits2f(unsigned hi_bits) {
    return __uint_as_float(hi_bits);
}
// tanh(x) = 1 - 2/(e^{2x}+1); exact at +/-inf, ~1e-7 rel error
static __device__ __forceinline__ float fast_tanh(float x) {
    float e = __expf(2.f * x);
    return 1.f - 2.f * __builtin_amdgcn_rcpf(e + 1.f);
}

// ---------------------------------------------------------------------------
// pack: B operands -> MFMA fragment order; also zeroes d_out (saves a launch).
// frag elem j of lane l, tile nt, step ks = B[ks*32 + (l>>4)*8 + j][nt*16 + (l&15)]
// ---------------------------------------------------------------------------
__global__ __launch_bounds__(256) void pack_kernel(const float* __restrict__ enc1,
                                                   const float* __restrict__ wgt,
                                                   const float* __restrict__ enc2,
                                                   short* __restrict__ Bp1,
                                                   short* __restrict__ Bp2,
                                                   float* __restrict__ out) {
    int tid = blockIdx.x * 256 + threadIdx.x;   // 0..8191
    if (tid < 8192) out[tid] = 0.f;             // B_*D_ = 8192
    short o8[8];
    if (tid < 4096) {
        int l = tid & 63, nt = (tid >> 6) & 7, ks = tid >> 9;   // ks 0..7
        int k0 = ks * 32 + (l >> 4) * 8;
        int col = nt * 16 + (l & 15);
#pragma unroll
        for (int j = 0; j < 8; ++j) {
            int r = k0 + j;
            float v = (r < 128) ? enc1[r * 128 + col] : wgt[(r - 128) * 128 + col];
            o8[j] = f2bf(v);
        }
        *(int4*)&Bp1[(size_t)tid * 8] = *(int4*)o8;
    } else if (tid < 6144) {
        int t2 = tid - 4096;
        int l = t2 & 63, nt = (t2 >> 6) & 7, ks = t2 >> 9;      // ks 0..3
        int k0 = ks * 32 + (l >> 4) * 8;
        int col = nt * 16 + (l & 15);
#pragma unroll
        for (int j = 0; j < 8; ++j) o8[j] = f2bf(enc2[(k0 + j) * 128 + col]);
        *(int4*)&Bp2[(size_t)t2 * 8] = *(int4*)o8;
    }
}

// XCD-aware swizzle: 2048 blocks, 32 per batch. XCD k (hw%8==k) gets logical
// blocks [256k,256k+256) = batches [8k,8k+8) -> per-XCD L2 working set ~3 MB.
static __device__ __forceinline__ int swz_blk() {
    const int hw = blockIdx.x;
    return ((hw & 7) << 8) + (hw >> 3);
}

// ---------------------------------------------------------------------------
// gemm1: base = [word | agg(lib,nbrL)] @ [enc1; weight] (K=256), t1 = tanh(base)
// 2048 blocks x 256 threads; block = 16 nodes (one MFMA row-tile).
// Wave w stages rows 4w..4w+3, computes col-tiles 2w, 2w+1.
// ---------------------------------------------------------------------------
#define LDA1 264   // 256 + 8 pad shorts
__global__ __launch_bounds__(256) void gemm1(const float* __restrict__ word,
                                             const int* __restrict__ nbrL,
                                             const float* __restrict__ lib,
                                             const short* __restrict__ Bp1,
                                             float* __restrict__ base,
                                             short* __restrict__ t1) {
    __shared__ short sA[NPB * LDA1];
    __shared__ int sIdx[NPB * 16];
    const int tid = threadIdx.x;
    const int blk = swz_blk();
    const int b = blk >> 5;
    const int node0 = blk * NPB;

    if (tid < 64) *(int4*)&sIdx[tid * 4] = *(const int4*)&nbrL[(size_t)node0 * 16 + tid * 4];
    __syncthreads();

    const int w = tid >> 6, l = tid & 63;
    const int rh = l >> 5, c4 = l & 31;         // row-half, 4-col group
    const float* libB = lib + (size_t)b * N_ * D_;

#pragma unroll
    for (int p = 0; p < 2; ++p) {
        const int row = 4 * w + 2 * p + rh;
        const int gid = node0 + row;
        float4 wv = *(const float4*)&word[(size_t)gid * D_ + c4 * 4];
        short4 ws; ws.x = f2bf(wv.x); ws.y = f2bf(wv.y); ws.z = f2bf(wv.z); ws.w = f2bf(wv.w);
        *(short4*)&sA[row * LDA1 + c4 * 4] = ws;
        int idxr[16];
#pragma unroll
        for (int k = 0; k < 16; ++k) idxr[k] = sIdx[row * 16 + k];
        float4 s = {0.f, 0.f, 0.f, 0.f};
#pragma unroll
        for (int k = 0; k < 16; ++k) {
            float4 lv = *(const float4*)&libB[(size_t)idxr[k] * D_ + c4 * 4];
            s.x += lv.x; s.y += lv.y; s.z += lv.z; s.w += lv.w;
        }
        short4 as; as.x = f2bf(s.x * 0.0625f); as.y = f2bf(s.y * 0.0625f);
        as.z = f2bf(s.z * 0.0625f); as.w = f2bf(s.w * 0.0625f);
        *(short4*)&sA[row * LDA1 + 128 + c4 * 4] = as;
    }
    __syncthreads();

    f32x4 acc[2];
    acc[0] = (f32x4)0.f; acc[1] = (f32x4)0.f;

    const int arow = l & 15;
#pragma unroll
    for (int ks = 0; ks < 8; ++ks) {
        bf16x8 a = *(const bf16x8*)&sA[arow * LDA1 + ks * 32 + (l >> 4) * 8];
#pragma unroll
        for (int j = 0; j < 2; ++j) {
            const int nt = 2 * w + j;
            bf16x8 bb = *(const bf16x8*)&Bp1[((size_t)(ks * 8 + nt) * 64 + l) * 8];
            acc[j] = __builtin_amdgcn_mfma_f32_16x16x32_bf16(a, bb, acc[j], 0, 0, 0);
        }
    }

    const int r0 = (l >> 4) * 4;
    const int cl = l & 15;
#pragma unroll
    for (int j = 0; j < 2; ++j) {
        const int col = (2 * w + j) * 16 + cl;
#pragma unroll
        for (int r = 0; r < 4; ++r) {
            size_t o = (size_t)(node0 + r0 + r) * D_ + col;
            float v = acc[j][r];
            base[o] = v;
            t1[o] = f2bf(fast_tanh(v));
        }
    }
}

// ---------------------------------------------------------------------------
// gemm2: t2 = tanh(base + agg(t1,nbr) @ enc2);
//        out[b] += (sum_n mask*t2) @ weight2   (kC fused, atomic into d_out)
// ---------------------------------------------------------------------------
#define LDA2 136   // 128 + 8 pad shorts
__global__ __launch_bounds__(256) void gemm2(const short* __restrict__ t1,
                                             const int* __restrict__ nbr,
                                             const short* __restrict__ Bp2,
                                             const float* __restrict__ base,
                                             const float* __restrict__ mask,
                                             const float* __restrict__ w2,
                                             float* __restrict__ out) {
    __shared__ short sA[NPB * LDA2];
    __shared__ int sIdx[NPB * 16];
    __shared__ float pred[128];
    const int tid = threadIdx.x;
    const int blk = swz_blk();
    const int b = blk >> 5;
    const int node0 = blk * NPB;

    if (tid < 64) *(int4*)&sIdx[tid * 4] = *(const int4*)&nbr[(size_t)node0 * 16 + tid * 4];
    __syncthreads();

    const int w = tid >> 6, l = tid & 63;
    const int rh = l >> 5, c4 = l & 31;
    const short* t1B = t1 + (size_t)b * N_ * D_;

#pragma unroll
    for (int p = 0; p < 2; ++p) {
        const int row = 4 * w + 2 * p + rh;
        int idxr[16];
#pragma unroll
        for (int k = 0; k < 16; ++k) idxr[k] = sIdx[row * 16 + k];
        float s0 = 0.f, s1 = 0.f, s2 = 0.f, s3 = 0.f;
#pragma unroll
        for (int k = 0; k < 16; ++k) {
            uint2 u = *(const uint2*)&t1B[(size_t)idxr[k] * D_ + c4 * 4];
            s0 += bfbits2f(u.x << 16); s1 += bfbits2f(u.x & 0xffff0000u);
            s2 += bfbits2f(u.y << 16); s3 += bfbits2f(u.y & 0xffff0000u);
        }
        short4 as; as.x = f2bf(s0 * 0.0625f); as.y = f2bf(s1 * 0.0625f);
        as.z = f2bf(s2 * 0.0625f); as.w = f2bf(s3 * 0.0625f);
        *(short4*)&sA[row * LDA2 + c4 * 4] = as;
    }
    __syncthreads();

    f32x4 acc[2];
    acc[0] = (f32x4)0.f; acc[1] = (f32x4)0.f;

    const int arow = l & 15;
#pragma unroll
    for (int ks = 0; ks < 4; ++ks) {
        bf16x8 a = *(const bf16x8*)&sA[arow * LDA2 + ks * 32 + (l >> 4) * 8];
#pragma unroll
        for (int j = 0; j < 2; ++j) {
            const int nt = 2 * w + j;
            bf16x8 bb = *(const bf16x8*)&Bp2[((size_t)(ks * 8 + nt) * 64 + l) * 8];
            acc[j] = __builtin_amdgcn_mfma_f32_16x16x32_bf16(a, bb, acc[j], 0, 0, 0);
        }
    }

    const int r0 = (l >> 4) * 4;
    const int cl = l & 15;
#pragma unroll
    for (int j = 0; j < 2; ++j) {
        const int col = (2 * w + j) * 16 + cl;
        float s = 0.f;
#pragma unroll
        for (int r = 0; r < 4; ++r) {
            size_t o = (size_t)(node0 + r0 + r) * D_ + col;
            float v = fast_tanh(base[o] + acc[j][r]);
            s += v * mask[node0 + r0 + r];
        }
        s += __shfl_xor(s, 16);
        s += __shfl_xor(s, 32);
        if (l < 16) pred[col] = s;
    }
    __syncthreads();
    if (tid < 128) {
        float a2 = 0.f;
#pragma unroll 4
        for (int f = 0; f < 128; ++f) a2 += pred[f] * w2[f * 128 + tid];
        atomicAdd(&out[b * 128 + tid], a2);
    }
}

extern "C" void kernel_launch(void* const* d_in, const int* in_sizes, int n_in,
                              void* d_out, int out_size, void* d_ws, size_t ws_size,
                              hipStream_t stream) {
    const float* word_embs   = (const float*)d_in[0];
    const int*   neibors     = (const int*)d_in[1];
    const float* lib_embs    = (const float*)d_in[2];
    const int*   neibors_lib = (const int*)d_in[3];
    const float* mask        = (const float*)d_in[4];
    const float* weight      = (const float*)d_in[5];
    const float* weight2     = (const float*)d_in[6];
    const float* enc_w1      = (const float*)d_in[7];
    const float* enc_w2      = (const float*)d_in[8];
    float* out = (float*)d_out;

    char* ws = (char*)d_ws;
    float* base = (float*)(ws);                              // 16 MB
    short* t1   = (short*)(ws + (1u << 24));                 // 8 MB bf16
    short* Bp1  = (short*)(ws + (1u << 24) + (1u << 23));    // 64 KB
    short* Bp2  = (short*)(ws + (1u << 24) + (1u << 23) + 65536);  // 32 KB

    pack_kernel<<<32, 256, 0, stream>>>(enc_w1, weight, enc_w2, Bp1, Bp2, out);
    gemm1<<<G1, 256, 0, stream>>>(word_embs, neibors_lib, lib_embs, Bp1, base, t1);
    gemm2<<<G1, 256, 0, stream>>>(t1, neibors, Bp2, base, mask, weight2, out);
}

// Round 7
// 49.594 us; speedup vs baseline: 2.9947x; 1.0341x over previous
//
#include <hip/hip_runtime.h>
#include <hip/hip_bf16.h>

#define B_   64
#define N_   512
#define K_   16
#define D_   128
#define NPB  16                 // nodes per block
#define G1   ((B_*N_)/NPB)      // 2048 blocks

typedef float f32x4  __attribute__((ext_vector_type(4)));
typedef short bf16x8 __attribute__((ext_vector_type(8)));

static __device__ __forceinline__ short f2bf(float x) {
    union { float f; unsigned u; } v; v.f = x;
    unsigned r = v.u + 0x7fffu + ((v.u >> 16) & 1u);  // RNE
    return (short)(r >> 16);
}
static __device__ __forceinline__ float bfbits2f(unsigned hi_bits) {
    return __uint_as_float(hi_bits);
}
static __device__ __forceinline__ float bf2f(short h) {
    return __uint_as_float(((unsigned)(unsigned short)h) << 16);
}
// tanh(x) = 1 - 2/(e^{2x}+1); exact at +/-inf, ~1e-7 rel error
static __device__ __forceinline__ float fast_tanh(float x) {
    float e = __expf(2.f * x);
    return 1.f - 2.f * __builtin_amdgcn_rcpf(e + 1.f);
}

// ---------------------------------------------------------------------------
// prep: blocks 0..1023  : lib_embs fp32 -> bf16 (4096 elems/block; 1024*4096 = B*N*D)
//       blocks 1024..1055: pack B operands to MFMA fragment order + zero d_out
// frag elem j of lane l, tile nt, step ks = B[ks*32 + (l>>4)*8 + j][nt*16 + (l&15)]
// ---------------------------------------------------------------------------
__global__ __launch_bounds__(256) void prep(const float* __restrict__ lib,
                                            const float* __restrict__ enc1,
                                            const float* __restrict__ wgt,
                                            const float* __restrict__ enc2,
                                            short* __restrict__ libh,
                                            short* __restrict__ Bp1,
                                            short* __restrict__ Bp2,
                                            float* __restrict__ out) {
    const int blk = blockIdx.x;
    if (blk < 1024) {
        const size_t g = ((size_t)blk * 256 + threadIdx.x) * 16;
        short o16[16];
#pragma unroll
        for (int q = 0; q < 4; ++q) {
            float4 v = *(const float4*)&lib[g + q * 4];
            o16[q * 4 + 0] = f2bf(v.x); o16[q * 4 + 1] = f2bf(v.y);
            o16[q * 4 + 2] = f2bf(v.z); o16[q * 4 + 3] = f2bf(v.w);
        }
        *(int4*)&libh[g]     = *(int4*)o16;
        *(int4*)&libh[g + 8] = *(int4*)(o16 + 8);
        return;
    }
    int tid = (blk - 1024) * 256 + threadIdx.x;   // 0..8191
    out[tid] = 0.f;                               // B_*D_ = 8192
    short o8[8];
    if (tid < 4096) {
        int l = tid & 63, nt = (tid >> 6) & 7, ks = tid >> 9;   // ks 0..7
        int k0 = ks * 32 + (l >> 4) * 8;
        int col = nt * 16 + (l & 15);
#pragma unroll
        for (int j = 0; j < 8; ++j) {
            int r = k0 + j;
            float v = (r < 128) ? enc1[r * 128 + col] : wgt[(r - 128) * 128 + col];
            o8[j] = f2bf(v);
        }
        *(int4*)&Bp1[(size_t)tid * 8] = *(int4*)o8;
    } else if (tid < 6144) {
        int t2 = tid - 4096;
        int l = t2 & 63, nt = (t2 >> 6) & 7, ks = t2 >> 9;      // ks 0..3
        int k0 = ks * 32 + (l >> 4) * 8;
        int col = nt * 16 + (l & 15);
#pragma unroll
        for (int j = 0; j < 8; ++j) o8[j] = f2bf(enc2[(k0 + j) * 128 + col]);
        *(int4*)&Bp2[(size_t)t2 * 8] = *(int4*)o8;
    }
}

// XCD-aware swizzle: 2048 blocks, 32 per batch. XCD k (hw%8==k) gets logical
// blocks [256k,256k+256) = batches [8k,8k+8) -> per-XCD L2 working set ~3 MB.
static __device__ __forceinline__ int swz_blk() {
    const int hw = blockIdx.x;
    return ((hw & 7) << 8) + (hw >> 3);
}

// ---------------------------------------------------------------------------
// gemm1: base = [word | agg(libh,nbrL)] @ [enc1; weight] (K=256), t1 = tanh(base)
// 2048 blocks x 256 threads; block = 16 nodes (one MFMA row-tile).
// base stored bf16 (halves write + reread traffic).
// ---------------------------------------------------------------------------
#define LDA1 264   // 256 + 8 pad shorts
__global__ __launch_bounds__(256) void gemm1(const float* __restrict__ word,
                                             const int* __restrict__ nbrL,
                                             const short* __restrict__ libh,
                                             const short* __restrict__ Bp1,
                                             short* __restrict__ baseh,
                                             short* __restrict__ t1) {
    __shared__ short sA[NPB * LDA1];
    __shared__ int sIdx[NPB * 16];
    const int tid = threadIdx.x;
    const int blk = swz_blk();
    const int b = blk >> 5;
    const int node0 = blk * NPB;

    if (tid < 64) *(int4*)&sIdx[tid * 4] = *(const int4*)&nbrL[(size_t)node0 * 16 + tid * 4];
    __syncthreads();

    const int w = tid >> 6, l = tid & 63;
    const int rh = l >> 5, c4 = l & 31;         // row-half, 4-col group
    const short* libB = libh + (size_t)b * N_ * D_;

#pragma unroll
    for (int p = 0; p < 2; ++p) {
        const int row = 4 * w + 2 * p + rh;
        const int gid = node0 + row;
        float4 wv = *(const float4*)&word[(size_t)gid * D_ + c4 * 4];
        short4 ws; ws.x = f2bf(wv.x); ws.y = f2bf(wv.y); ws.z = f2bf(wv.z); ws.w = f2bf(wv.w);
        *(short4*)&sA[row * LDA1 + c4 * 4] = ws;
        int idxr[16];
#pragma unroll
        for (int k = 0; k < 16; ++k) idxr[k] = sIdx[row * 16 + k];
        float s0 = 0.f, s1 = 0.f, s2 = 0.f, s3 = 0.f;
#pragma unroll
        for (int k = 0; k < 16; ++k) {
            uint2 u = *(const uint2*)&libB[(size_t)idxr[k] * D_ + c4 * 4];
            s0 += bfbits2f(u.x << 16); s1 += bfbits2f(u.x & 0xffff0000u);
            s2 += bfbits2f(u.y << 16); s3 += bfbits2f(u.y & 0xffff0000u);
        }
        short4 as; as.x = f2bf(s0 * 0.0625f); as.y = f2bf(s1 * 0.0625f);
        as.z = f2bf(s2 * 0.0625f); as.w = f2bf(s3 * 0.0625f);
        *(short4*)&sA[row * LDA1 + 128 + c4 * 4] = as;
    }
    __syncthreads();

    f32x4 acc[2];
    acc[0] = (f32x4)0.f; acc[1] = (f32x4)0.f;

    const int arow = l & 15;
#pragma unroll
    for (int ks = 0; ks < 8; ++ks) {
        bf16x8 a = *(const bf16x8*)&sA[arow * LDA1 + ks * 32 + (l >> 4) * 8];
#pragma unroll
        for (int j = 0; j < 2; ++j) {
            const int nt = 2 * w + j;
            bf16x8 bb = *(const bf16x8*)&Bp1[((size_t)(ks * 8 + nt) * 64 + l) * 8];
            acc[j] = __builtin_amdgcn_mfma_f32_16x16x32_bf16(a, bb, acc[j], 0, 0, 0);
        }
    }

    const int r0 = (l >> 4) * 4;
    const int cl = l & 15;
#pragma unroll
    for (int j = 0; j < 2; ++j) {
        const int col = (2 * w + j) * 16 + cl;
#pragma unroll
        for (int r = 0; r < 4; ++r) {
            size_t o = (size_t)(node0 + r0 + r) * D_ + col;
            float v = acc[j][r];
            baseh[o] = f2bf(v);
            t1[o]    = f2bf(fast_tanh(v));
        }
    }
}

// ---------------------------------------------------------------------------
// gemm2: t2 = tanh(base + agg(t1,nbr) @ enc2);
//        out[b] += (sum_n mask*t2) @ weight2   (kC fused, atomic into d_out)
// ---------------------------------------------------------------------------
#define LDA2 136   // 128 + 8 pad shorts
__global__ __launch_bounds__(256) void gemm2(const short* __restrict__ t1,
                                             const int* __restrict__ nbr,
                                             const short* __restrict__ Bp2,
                                             const short* __restrict__ baseh,
                                             const float* __restrict__ mask,
                                             const float* __restrict__ w2,
                                             float* __restrict__ out) {
    __shared__ short sA[NPB * LDA2];
    __shared__ int sIdx[NPB * 16];
    __shared__ float pred[128];
    __shared__ float smask[NPB];
    const int tid = threadIdx.x;
    const int blk = swz_blk();
    const int b = blk >> 5;
    const int node0 = blk * NPB;

    if (tid < 64) *(int4*)&sIdx[tid * 4] = *(const int4*)&nbr[(size_t)node0 * 16 + tid * 4];
    if (tid >= 64 && tid < 64 + NPB) smask[tid - 64] = mask[node0 + tid - 64];
    __syncthreads();

    const int w = tid >> 6, l = tid & 63;
    const int rh = l >> 5, c4 = l & 31;
    const short* t1B = t1 + (size_t)b * N_ * D_;

#pragma unroll
    for (int p = 0; p < 2; ++p) {
        const int row = 4 * w + 2 * p + rh;
        int idxr[16];
#pragma unroll
        for (int k = 0; k < 16; ++k) idxr[k] = sIdx[row * 16 + k];
        float s0 = 0.f, s1 = 0.f, s2 = 0.f, s3 = 0.f;
#pragma unroll
        for (int k = 0; k < 16; ++k) {
            uint2 u = *(const uint2*)&t1B[(size_t)idxr[k] * D_ + c4 * 4];
            s0 += bfbits2f(u.x << 16); s1 += bfbits2f(u.x & 0xffff0000u);
            s2 += bfbits2f(u.y << 16); s3 += bfbits2f(u.y & 0xffff0000u);
        }
        short4 as; as.x = f2bf(s0 * 0.0625f); as.y = f2bf(s1 * 0.0625f);
        as.z = f2bf(s2 * 0.0625f); as.w = f2bf(s3 * 0.0625f);
        *(short4*)&sA[row * LDA2 + c4 * 4] = as;
    }
    __syncthreads();

    f32x4 acc[2];
    acc[0] = (f32x4)0.f; acc[1] = (f32x4)0.f;

    const int arow = l & 15;
#pragma unroll
    for (int ks = 0; ks < 4; ++ks) {
        bf16x8 a = *(const bf16x8*)&sA[arow * LDA2 + ks * 32 + (l >> 4) * 8];
#pragma unroll
        for (int j = 0; j < 2; ++j) {
            const int nt = 2 * w + j;
            bf16x8 bb = *(const bf16x8*)&Bp2[((size_t)(ks * 8 + nt) * 64 + l) * 8];
            acc[j] = __builtin_amdgcn_mfma_f32_16x16x32_bf16(a, bb, acc[j], 0, 0, 0);
        }
    }

    const int r0 = (l >> 4) * 4;
    const int cl = l & 15;
#pragma unroll
    for (int j = 0; j < 2; ++j) {
        const int col = (2 * w + j) * 16 + cl;
        float s = 0.f;
#pragma unroll
        for (int r = 0; r < 4; ++r) {
            size_t o = (size_t)(node0 + r0 + r) * D_ + col;
            float v = fast_tanh(bf2f(baseh[o]) + acc[j][r]);
            s += v * smask[r0 + r];
        }
        s += __shfl_xor(s, 16);
        s += __shfl_xor(s, 32);
        if (l < 16) pred[col] = s;
    }
    __syncthreads();
    if (tid < 128) {
        float a2 = 0.f;
#pragma unroll 4
        for (int f = 0; f < 128; ++f) a2 += pred[f] * w2[f * 128 + tid];
        atomicAdd(&out[b * 128 + tid], a2);
    }
}

extern "C" void kernel_launch(void* const* d_in, const int* in_sizes, int n_in,
                              void* d_out, int out_size, void* d_ws, size_t ws_size,
                              hipStream_t stream) {
    const float* word_embs   = (const float*)d_in[0];
    const int*   neibors     = (const int*)d_in[1];
    const float* lib_embs    = (const float*)d_in[2];
    const int*   neibors_lib = (const int*)d_in[3];
    const float* mask        = (const float*)d_in[4];
    const float* weight      = (const float*)d_in[5];
    const float* weight2     = (const float*)d_in[6];
    const float* enc_w1      = (const float*)d_in[7];
    const float* enc_w2      = (const float*)d_in[8];
    float* out = (float*)d_out;

    char* ws = (char*)d_ws;
    short* baseh = (short*)(ws);                             // 8 MB
    short* t1    = (short*)(ws + (1u << 23));                // 8 MB
    short* libh  = (short*)(ws + (2u << 23));                // 8 MB
    short* Bp1   = (short*)(ws + (3u << 23));                // 64 KB
    short* Bp2   = (short*)(ws + (3u << 23) + 65536);        // 32 KB

    prep<<<1056, 256, 0, stream>>>(lib_embs, enc_w1, weight, enc_w2, libh, Bp1, Bp2, out);
    gemm1<<<G1, 256, 0, stream>>>(word_embs, neibors_lib, libh, Bp1, baseh, t1);
    gemm2<<<G1, 256, 0, stream>>>(t1, neibors, Bp2, baseh, mask, weight2, out);
}